// Round 3
// baseline (234.375 us; speedup 1.0000x reference)
//
#include <hip/hip_runtime.h>

#define NROWS 4096
#define DCOLS 4096
#define MARGIN 1.2f

// 1024 blocks x 256 threads; each 64-lane wave owns one row (4096 waves total).
// loss_i = y_i * d2 + (1-y_i) * max(0, MARGIN - sqrt(d2)),  d2 = ||x0_i - x1_i||^2
// Wave shuffle-reduces d2, lane 0 atomically adds loss_i/(2N) into out[0].
// No LDS, no __syncthreads -> waves retire independently; few, fat blocks
// (round 1/2 evidence: dur ~independent of HBM vs L3 residency => per-block
// fixed overhead dominated at 4096 blocks).
__global__ __launch_bounds__(256) void row_loss_kernel(
    const float* __restrict__ x0, const float* __restrict__ x1,
    const int* __restrict__ y, float* __restrict__ out) {
    const int lane = threadIdx.x & 63;
    const int row = (blockIdx.x << 2) | (threadIdx.x >> 6);

    const float4* __restrict__ a = (const float4*)(x0 + (size_t)row * DCOLS);
    const float4* __restrict__ b = (const float4*)(x1 + (size_t)row * DCOLS);

    float s0 = 0.f, s1 = 0.f, s2 = 0.f, s3 = 0.f;
    // 1024 float4 per row / 64 lanes = 16 per lane; 4 batches of 4 pairs,
    // 8 independent 16B loads per batch in flight.
    #pragma unroll
    for (int batch = 0; batch < 4; ++batch) {
        const int base = batch * 256 + lane;
        float4 va0 = a[base];
        float4 va1 = a[base + 64];
        float4 va2 = a[base + 128];
        float4 va3 = a[base + 192];
        float4 vb0 = b[base];
        float4 vb1 = b[base + 64];
        float4 vb2 = b[base + 128];
        float4 vb3 = b[base + 192];
        float d;
        d = va0.x - vb0.x; s0 = fmaf(d, d, s0);
        d = va0.y - vb0.y; s1 = fmaf(d, d, s1);
        d = va0.z - vb0.z; s2 = fmaf(d, d, s2);
        d = va0.w - vb0.w; s3 = fmaf(d, d, s3);
        d = va1.x - vb1.x; s0 = fmaf(d, d, s0);
        d = va1.y - vb1.y; s1 = fmaf(d, d, s1);
        d = va1.z - vb1.z; s2 = fmaf(d, d, s2);
        d = va1.w - vb1.w; s3 = fmaf(d, d, s3);
        d = va2.x - vb2.x; s0 = fmaf(d, d, s0);
        d = va2.y - vb2.y; s1 = fmaf(d, d, s1);
        d = va2.z - vb2.z; s2 = fmaf(d, d, s2);
        d = va2.w - vb2.w; s3 = fmaf(d, d, s3);
        d = va3.x - vb3.x; s0 = fmaf(d, d, s0);
        d = va3.y - vb3.y; s1 = fmaf(d, d, s1);
        d = va3.z - vb3.z; s2 = fmaf(d, d, s2);
        d = va3.w - vb3.w; s3 = fmaf(d, d, s3);
    }
    float s = (s0 + s1) + (s2 + s3);

    // wave64 reduction (no LDS needed; wave == row)
    #pragma unroll
    for (int off = 32; off > 0; off >>= 1) s += __shfl_down(s, off, 64);

    if (lane == 0) {
        float d2 = s;
        float dist = sqrtf(d2);
        float clamped = fmaxf(MARGIN - dist, 0.f);
        float yf = (float)y[row];
        float loss = yf * d2 + (1.f - yf) * clamped;
        atomicAdd(out, loss * (1.f / (2.f * (float)NROWS)));
    }
}

extern "C" void kernel_launch(void* const* d_in, const int* in_sizes, int n_in,
                              void* d_out, int out_size, void* d_ws, size_t ws_size,
                              hipStream_t stream) {
    const float* x0 = (const float*)d_in[0];
    const float* x1 = (const float*)d_in[1];
    // d_in[2], d_in[3] (x_c_0, x_c_1) are dead in the reference computation.
    const int* y = (const int*)d_in[4];
    float* out = (float*)d_out;

    hipMemsetAsync(out, 0, (size_t)out_size * sizeof(float), stream);
    row_loss_kernel<<<NROWS / 4, 256, 0, stream>>>(x0, x1, y, out);
}

// Round 4
// 212.638 us; speedup vs baseline: 1.1022x; 1.1022x over previous
//
#include <hip/hip_runtime.h>

#define NROWS 4096
#define DCOLS 4096
#define MARGIN 1.2f

// One block per row, with XCD-aware swizzle: blocks are dispatched round-robin
// across 8 XCDs, so map blockIdx -> row such that each XCD sweeps a contiguous
// 512-row (8 MB) band instead of a 128 KB-strided comb (power-of-2 stride
// aliases L3/memory channels -> ~3 B/cyc/CU observed in R1-R3).
__global__ __launch_bounds__(256) void row_loss_kernel(
    const float* __restrict__ x0, const float* __restrict__ x1,
    const int* __restrict__ y, float* __restrict__ row_out) {
    const int row = ((blockIdx.x & 7) << 9) | (blockIdx.x >> 3);
    const float4* __restrict__ a = (const float4*)(x0 + (size_t)row * DCOLS);
    const float4* __restrict__ b = (const float4*)(x1 + (size_t)row * DCOLS);

    float s = 0.f;
    // 1024 float4 per row / 256 threads = 4 iters, coalesced (R1's fastest form).
    #pragma unroll 4
    for (int i = threadIdx.x; i < DCOLS / 4; i += 256) {
        float4 va = a[i];
        float4 vb = b[i];
        float dx = va.x - vb.x;
        float dy = va.y - vb.y;
        float dz = va.z - vb.z;
        float dw = va.w - vb.w;
        s = fmaf(dx, dx, s);
        s = fmaf(dy, dy, s);
        s = fmaf(dz, dz, s);
        s = fmaf(dw, dw, s);
    }

    // wave64 reduction
    #pragma unroll
    for (int off = 32; off > 0; off >>= 1) s += __shfl_down(s, off, 64);

    __shared__ float smem[4];
    const int lane = threadIdx.x & 63;
    const int wid = threadIdx.x >> 6;
    if (lane == 0) smem[wid] = s;
    __syncthreads();

    if (threadIdx.x == 0) {
        float d2 = (smem[0] + smem[1]) + (smem[2] + smem[3]);
        float dist = sqrtf(d2);
        float clamped = fmaxf(MARGIN - dist, 0.f);
        float yf = (float)y[row];
        row_out[row] = yf * d2 + (1.f - yf) * clamped;
    }
}

__global__ __launch_bounds__(256) void final_reduce_kernel(
    const float* __restrict__ row_out, float* __restrict__ out) {
    float s = 0.f;
    for (int i = threadIdx.x; i < NROWS; i += 256) s += row_out[i];

    #pragma unroll
    for (int off = 32; off > 0; off >>= 1) s += __shfl_down(s, off, 64);

    __shared__ float smem[4];
    const int lane = threadIdx.x & 63;
    const int wid = threadIdx.x >> 6;
    if (lane == 0) smem[wid] = s;
    __syncthreads();

    if (threadIdx.x == 0) {
        out[0] = ((smem[0] + smem[1]) + (smem[2] + smem[3])) * (1.f / (2.f * (float)NROWS));
    }
}

extern "C" void kernel_launch(void* const* d_in, const int* in_sizes, int n_in,
                              void* d_out, int out_size, void* d_ws, size_t ws_size,
                              hipStream_t stream) {
    const float* x0 = (const float*)d_in[0];
    const float* x1 = (const float*)d_in[1];
    // d_in[2], d_in[3] (x_c_0, x_c_1) are dead in the reference computation.
    const int* y = (const int*)d_in[4];

    float* row_out = (float*)d_ws;  // 4096 floats = 16 KiB scratch
    float* out = (float*)d_out;

    row_loss_kernel<<<NROWS, 256, 0, stream>>>(x0, x1, y, row_out);
    final_reduce_kernel<<<1, 256, 0, stream>>>(row_out, out);
}

// Round 6
// 197.367 us; speedup vs baseline: 1.1875x; 1.0774x over previous
//
#include <hip/hip_runtime.h>

#define NROWS 4096
#define DCOLS 4096
#define MARGIN 1.2f

// Native clang vector type — __builtin_nontemporal_load rejects the
// HIP_vector_type<float,4> class but accepts ext_vector_type.
typedef float vfloat4 __attribute__((ext_vector_type(4)));

// R1 structure (fastest observed: 48us), natural block->row mapping, with
// NON-TEMPORAL loads for the streaming x0/x1 reads. Theory: harness restores
// 256 MB of inputs before each replay, leaving L3 full of dirty lines; normal
// read-misses allocate L3 lines and force dirty-victim writebacks, capping
// delivered BW at ~2.8 TB/s regardless of kernel structure (R1-R4 evidence).
// nt loads skip allocation -> no victim traffic.
__global__ __launch_bounds__(256) void row_loss_kernel(
    const float* __restrict__ x0, const float* __restrict__ x1,
    const int* __restrict__ y, float* __restrict__ row_out) {
    const int row = blockIdx.x;
    const vfloat4* __restrict__ a = (const vfloat4*)(x0 + (size_t)row * DCOLS);
    const vfloat4* __restrict__ b = (const vfloat4*)(x1 + (size_t)row * DCOLS);

    float s = 0.f;
    // 1024 float4 per row / 256 threads = 4 iters, coalesced.
    #pragma unroll 4
    for (int i = threadIdx.x; i < DCOLS / 4; i += 256) {
        vfloat4 va = __builtin_nontemporal_load(a + i);
        vfloat4 vb = __builtin_nontemporal_load(b + i);
        float dx = va.x - vb.x;
        float dy = va.y - vb.y;
        float dz = va.z - vb.z;
        float dw = va.w - vb.w;
        s = fmaf(dx, dx, s);
        s = fmaf(dy, dy, s);
        s = fmaf(dz, dz, s);
        s = fmaf(dw, dw, s);
    }

    // wave64 reduction
    #pragma unroll
    for (int off = 32; off > 0; off >>= 1) s += __shfl_down(s, off, 64);

    __shared__ float smem[4];
    const int lane = threadIdx.x & 63;
    const int wid = threadIdx.x >> 6;
    if (lane == 0) smem[wid] = s;
    __syncthreads();

    if (threadIdx.x == 0) {
        float d2 = (smem[0] + smem[1]) + (smem[2] + smem[3]);
        float dist = sqrtf(d2);
        float clamped = fmaxf(MARGIN - dist, 0.f);
        float yf = (float)y[row];
        row_out[row] = yf * d2 + (1.f - yf) * clamped;
    }
}

__global__ __launch_bounds__(256) void final_reduce_kernel(
    const float* __restrict__ row_out, float* __restrict__ out) {
    float s = 0.f;
    for (int i = threadIdx.x; i < NROWS; i += 256) s += row_out[i];

    #pragma unroll
    for (int off = 32; off > 0; off >>= 1) s += __shfl_down(s, off, 64);

    __shared__ float smem[4];
    const int lane = threadIdx.x & 63;
    const int wid = threadIdx.x >> 6;
    if (lane == 0) smem[wid] = s;
    __syncthreads();

    if (threadIdx.x == 0) {
        out[0] = ((smem[0] + smem[1]) + (smem[2] + smem[3])) * (1.f / (2.f * (float)NROWS));
    }
}

extern "C" void kernel_launch(void* const* d_in, const int* in_sizes, int n_in,
                              void* d_out, int out_size, void* d_ws, size_t ws_size,
                              hipStream_t stream) {
    const float* x0 = (const float*)d_in[0];
    const float* x1 = (const float*)d_in[1];
    // d_in[2], d_in[3] (x_c_0, x_c_1) are dead in the reference computation.
    const int* y = (const int*)d_in[4];

    float* row_out = (float*)d_ws;  // 4096 floats = 16 KiB scratch
    float* out = (float*)d_out;

    row_loss_kernel<<<NROWS, 256, 0, stream>>>(x0, x1, y, row_out);
    final_reduce_kernel<<<1, 256, 0, stream>>>(row_out, out);
}